// Round 2
// baseline (258.932 us; speedup 1.0000x reference)
//
#include <hip/hip_runtime.h>
#include <hip/hip_cooperative_groups.h>
#include <math.h>

namespace cg = cooperative_groups;

#define EPSV 1e-12f

// One cooperative kernel:
//  phase 0: zero sums[D] in ws
//  phase 1: column-sum of hidden over S via per-thread row-chunk + atomicAdd
//  phase 2: per-block redundant scalar reduction (dot products) -> alpha etc.
//  phase 3: out = hidden + coef(s) * (c-i)/||c-i||
__global__ __launch_bounds__(256, 4)
void ara_fused(const float* __restrict__ hid, const float* __restrict__ cdir,
               const float* __restrict__ idir, const float* __restrict__ sscale,
               float* __restrict__ out, float* __restrict__ sums,
               int S, int D4) {
    cg::grid_group grid = cg::this_grid();
    const float4* h4 = reinterpret_cast<const float4*>(hid);
    const float4* c4p = reinterpret_cast<const float4*>(cdir);
    const float4* i4p = reinterpret_cast<const float4*>(idir);
    const float4* s4p = reinterpret_cast<const float4*>(sums);
    float4* o4 = reinterpret_cast<float4*>(out);

    const int tid = threadIdx.x;
    const int bid = blockIdx.x;
    const int nthreads = gridDim.x * blockDim.x;
    const int gt = bid * blockDim.x + tid;
    const int D = D4 * 4;

    // ---- phase 0: zero the accumulator ----
    for (int i = gt; i < D; i += nthreads) sums[i] = 0.f;
    grid.sync();

    // ---- phase 1: column sums (HBM read of hidden, 128 MiB) ----
    {
        int nchunk = nthreads / D4;                       // 256
        int rows_per_chunk = (S + nchunk - 1) / nchunk;   // 32
        int c4 = gt % D4;
        int chunk = gt / D4;
        long row0 = (long)chunk * rows_per_chunk;
        float4 acc = make_float4(0.f, 0.f, 0.f, 0.f);
        for (int r = 0; r < rows_per_chunk; ++r) {
            long row = row0 + r;
            if (row < S) {
                float4 v = h4[row * (long)D4 + c4];
                acc.x += v.x; acc.y += v.y; acc.z += v.z; acc.w += v.w;
            }
        }
        atomicAdd(&sums[4 * c4 + 0], acc.x);
        atomicAdd(&sums[4 * c4 + 1], acc.y);
        atomicAdd(&sums[4 * c4 + 2], acc.z);
        atomicAdd(&sums[4 * c4 + 3], acc.w);
    }
    grid.sync();

    // ---- phase 2: per-block redundant scalar reduction ----
    __shared__ float red[6][4];
    __shared__ float bcast[3];
    {
        float sc2 = 0.f, si2 = 0.f, scd = 0.f, sid = 0.f, scur2 = 0.f, sd2 = 0.f;
        for (int d4 = tid; d4 < D4; d4 += blockDim.x) {
            float4 c = c4p[d4], iv = i4p[d4], sm = s4p[d4];
            sc2 += c.x * c.x + c.y * c.y + c.z * c.z + c.w * c.w;
            si2 += iv.x * iv.x + iv.y * iv.y + iv.z * iv.z + iv.w * iv.w;
            scd += sm.x * c.x + sm.y * c.y + sm.z * c.z + sm.w * c.w;
            sid += sm.x * iv.x + sm.y * iv.y + sm.z * iv.z + sm.w * iv.w;
            scur2 += sm.x * sm.x + sm.y * sm.y + sm.z * sm.z + sm.w * sm.w;
            float dx = c.x - iv.x, dy = c.y - iv.y, dz = c.z - iv.z, dw = c.w - iv.w;
            sd2 += dx * dx + dy * dy + dz * dz + dw * dw;
        }
        float vals[6] = {sc2, si2, scd, sid, scur2, sd2};
        int lane = tid & 63;
        int wid = tid >> 6;
#pragma unroll
        for (int k = 0; k < 6; ++k) {
            float v = vals[k];
#pragma unroll
            for (int o = 32; o > 0; o >>= 1) v += __shfl_down(v, o, 64);
            if (lane == 0) red[k][wid] = v;
        }
        __syncthreads();
        if (tid == 0) {
            float t[6];
#pragma unroll
            for (int k = 0; k < 6; ++k)
                t[k] = red[k][0] + red[k][1] + red[k][2] + red[k][3];
            float invS = 1.0f / (float)S;
            float cn = sqrtf(t[4]) * invS;                  // ||mean||
            float inv_cn = 1.0f / fmaxf(cn, EPSV);
            float csim = (sqrtf(t[0]) > 0.f) ? (t[2] * invS * inv_cn) : 0.f;
            float isim = (sqrtf(t[1]) > 0.f) ? (t[3] * invS * inv_cn) : 0.f;
            float quality = csim - isim;
            float amp = 0.5f * (0.1f - quality) / (0.1f + 0.3f);
            float alpha = (quality < -0.3f) ? 0.5f : ((quality < 0.1f) ? amp : 0.05f);
            float ndiff = sqrtf(t[5]);
            float inv_nd = 1.0f / fmaxf(ndiff, EPSV);
            bcast[0] = alpha * sscale[0];   // a_s
            bcast[1] = inv_nd;
            bcast[2] = ndiff * inv_nd;      // ||momentum||
        }
        __syncthreads();
    }
    const float a_s = bcast[0], inv_nd = bcast[1], mnorm = bcast[2];
    const float invS = 1.0f / (float)S;

    // ---- phase 3: apply (L3 re-read of hidden + HBM write of out) ----
    {
        int rows_per_block = (S + gridDim.x - 1) / gridDim.x;  // 8
        long row0 = (long)bid * rows_per_block;
        int jcols = D4 >> 8;                                    // strips of 256 float4
        // momentum (pre-scaled by inv_nd) cached in registers, up to 4 strips
        float4 mv[4];
        for (int j = 0; j < jcols && j < 4; ++j) {
            int d4 = (j << 8) + tid;
            float4 c = c4p[d4], iv = i4p[d4];
            mv[j].x = (c.x - iv.x) * inv_nd;
            mv[j].y = (c.y - iv.y) * inv_nd;
            mv[j].z = (c.z - iv.z) * inv_nd;
            mv[j].w = (c.w - iv.w) * inv_nd;
        }
        for (int r = 0; r < rows_per_block; ++r) {
            long s = row0 + r;
            if (s >= S) break;
            float eff = a_s * (0.5f + 0.5f * ((float)s * invS));
            float dn = fabsf(eff) * mnorm;
            float coef = (dn > 0.5f) ? (eff * (0.5f / dn)) : eff;
            for (int j = 0; j < jcols; ++j) {
                long idx = s * (long)D4 + (j << 8) + tid;
                float4 h = h4[idx];
                float4 m = mv[j & 3];
                float4 rr;
                rr.x = h.x + coef * m.x;
                rr.y = h.y + coef * m.y;
                rr.z = h.z + coef * m.z;
                rr.w = h.w + coef * m.w;
                o4[idx] = rr;
            }
        }
    }
}

extern "C" void kernel_launch(void* const* d_in, const int* in_sizes, int n_in,
                              void* d_out, int out_size, void* d_ws, size_t ws_size,
                              hipStream_t stream) {
    const float* hid    = (const float*)d_in[0];
    const float* cdir   = (const float*)d_in[1];
    const float* idir   = (const float*)d_in[2];
    const float* sscale = (const float*)d_in[3];
    float* out = (float*)d_out;

    int D = in_sizes[1];                 // 4096
    long total = (long)in_sizes[0];      // B*S*D, B=1
    int S = (int)(total / D);            // 8192
    int D4 = D / 4;

    float* sums = (float*)d_ws;          // D floats

    dim3 grid(1024), block(256);
    void* args[] = { (void*)&hid, (void*)&cdir, (void*)&idir, (void*)&sscale,
                     (void*)&out, (void*)&sums, (void*)&S, (void*)&D4 };
    hipLaunchCooperativeKernel((void*)ara_fused, grid, block, args, 0, stream);
}

// Round 4
// 102.674 us; speedup vs baseline: 2.5219x; 2.5219x over previous
//
#include <hip/hip_runtime.h>
#include <math.h>

#define EPSV 1e-12f

typedef float nfloat4 __attribute__((ext_vector_type(4)));

// ---------- Kernel 1: partial column sums (deterministic, no atomics) ----------
// grid = (ceil(D4/256), C). partial[c][D] as float4.
__global__ __launch_bounds__(256)
void ara_colsum(const float* __restrict__ hid, float* __restrict__ partial,
                int D4, int S, int rows_per_chunk) {
    int d4 = blockIdx.x * 256 + threadIdx.x;
    if (d4 >= D4) return;
    int c = blockIdx.y;
    const float4* h4 = reinterpret_cast<const float4*>(hid);
    float4* p4 = reinterpret_cast<float4*>(partial);
    long row0 = (long)c * rows_per_chunk;
    float4 acc = make_float4(0.f, 0.f, 0.f, 0.f);
#pragma unroll 8
    for (int r = 0; r < rows_per_chunk; ++r) {
        long row = row0 + r;
        if (row < S) {
            float4 v = h4[row * (long)D4 + d4];
            acc.x += v.x; acc.y += v.y; acc.z += v.z; acc.w += v.w;
        }
    }
    p4[(long)c * D4 + d4] = acc;
}

// ---------- Kernel 2: reduce partials + 6 dot products ----------
// grid = NB = ceil(D4/64) blocks x 256 threads. Block b owns float4 cols
// [b*64, b*64+64). 4 thread-groups of 64 lanes each sum C/4 chunks.
// Writes ws6[b][6] = {||c||^2, ||i||^2, sums.c, sums.i, ||sums||^2, ||c-i||^2}.
__global__ __launch_bounds__(256)
void ara_reduce(const float* __restrict__ partial, const float* __restrict__ cdir,
                const float* __restrict__ idir, float* __restrict__ ws6,
                int D4, int C) {
    const float4* p4 = reinterpret_cast<const float4*>(partial);
    const float4* c4p = reinterpret_cast<const float4*>(cdir);
    const float4* i4p = reinterpret_cast<const float4*>(idir);
    int lane = threadIdx.x & 63;
    int g = threadIdx.x >> 6;                 // 0..3
    int col = blockIdx.x * 64 + lane;
    bool valid = col < D4;
    int per = (C + 3) / 4;
    float4 acc = make_float4(0.f, 0.f, 0.f, 0.f);
    if (valid) {
        for (int j = 0; j < per; ++j) {
            int c = g * per + j;
            if (c < C) {
                float4 v = p4[(long)c * D4 + col];
                acc.x += v.x; acc.y += v.y; acc.z += v.z; acc.w += v.w;
            }
        }
    }
    __shared__ float4 lds[4][64];
    lds[g][lane] = acc;
    __syncthreads();
    if (threadIdx.x < 64) {
        float vals[6] = {0.f, 0.f, 0.f, 0.f, 0.f, 0.f};
        if (valid) {
            float4 s;
            s.x = lds[0][lane].x + lds[1][lane].x + lds[2][lane].x + lds[3][lane].x;
            s.y = lds[0][lane].y + lds[1][lane].y + lds[2][lane].y + lds[3][lane].y;
            s.z = lds[0][lane].z + lds[1][lane].z + lds[2][lane].z + lds[3][lane].z;
            s.w = lds[0][lane].w + lds[1][lane].w + lds[2][lane].w + lds[3][lane].w;
            float4 c = c4p[col], iv = i4p[col];
            vals[0] = c.x*c.x + c.y*c.y + c.z*c.z + c.w*c.w;
            vals[1] = iv.x*iv.x + iv.y*iv.y + iv.z*iv.z + iv.w*iv.w;
            vals[2] = s.x*c.x + s.y*c.y + s.z*c.z + s.w*c.w;
            vals[3] = s.x*iv.x + s.y*iv.y + s.z*iv.z + s.w*iv.w;
            vals[4] = s.x*s.x + s.y*s.y + s.z*s.z + s.w*s.w;
            float dx = c.x-iv.x, dy = c.y-iv.y, dz = c.z-iv.z, dw = c.w-iv.w;
            vals[5] = dx*dx + dy*dy + dz*dz + dw*dw;
        }
#pragma unroll
        for (int k = 0; k < 6; ++k) {
            float v = vals[k];
#pragma unroll
            for (int o = 32; o > 0; o >>= 1) v += __shfl_down(v, o, 64);
            if (lane == 0) ws6[blockIdx.x * 6 + k] = v;
        }
    }
}

// ---------- Kernel 3: apply ----------
// grid = ceil(S/rows_per_block) x 256. Per-block preamble sums ws6 (deterministic)
// and computes alpha; main loop streams rows with NT stores.
__global__ __launch_bounds__(256)
void ara_apply(const float* __restrict__ hid, const float* __restrict__ cdir,
               const float* __restrict__ idir, const float* __restrict__ sscale,
               const float* __restrict__ ws6, float* __restrict__ out,
               int D4, int S, int NB, int rows_per_block) {
    __shared__ float lds[256];
    __shared__ float bc[3];
    int tid = threadIdx.x;
    int n6 = NB * 6;
    if (tid < n6 && tid < 256) lds[tid] = ws6[tid];
    __syncthreads();
    if (tid == 0) {
        float t[6] = {0.f, 0.f, 0.f, 0.f, 0.f, 0.f};
        for (int b = 0; b < NB; ++b)
#pragma unroll
            for (int k = 0; k < 6; ++k) t[k] += lds[b * 6 + k];
        float invS = 1.0f / (float)S;
        float cn = sqrtf(t[4]) * invS;                  // ||mean||
        float inv_cn = 1.0f / fmaxf(cn, EPSV);
        float csim = (sqrtf(t[0]) > 0.f) ? (t[2] * invS * inv_cn) : 0.f;
        float isim = (sqrtf(t[1]) > 0.f) ? (t[3] * invS * inv_cn) : 0.f;
        float quality = csim - isim;
        float amp = 0.5f * (0.1f - quality) / (0.1f + 0.3f);
        float alpha = (quality < -0.3f) ? 0.5f : ((quality < 0.1f) ? amp : 0.05f);
        float ndiff = sqrtf(t[5]);
        float inv_nd = 1.0f / fmaxf(ndiff, EPSV);
        bc[0] = alpha * sscale[0];
        bc[1] = inv_nd;
        bc[2] = ndiff * inv_nd;                         // ||momentum||
    }
    __syncthreads();
    const float a_s = bc[0], inv_nd = bc[1], mnorm = bc[2];
    const float invS = 1.0f / (float)S;

    const float4* h4 = reinterpret_cast<const float4*>(hid);
    const float4* c4p = reinterpret_cast<const float4*>(cdir);
    const float4* i4p = reinterpret_cast<const float4*>(idir);
    nfloat4* o4 = reinterpret_cast<nfloat4*>(out);

    int jn = D4 >> 8;                                   // strips of 256 float4
    float4 mv[4];
    bool cached = (jn <= 4);
    for (int j = 0; j < jn && j < 4; ++j) {
        int d4 = (j << 8) + tid;
        float4 c = c4p[d4], iv = i4p[d4];
        mv[j].x = (c.x - iv.x) * inv_nd;
        mv[j].y = (c.y - iv.y) * inv_nd;
        mv[j].z = (c.z - iv.z) * inv_nd;
        mv[j].w = (c.w - iv.w) * inv_nd;
    }
    long row0 = (long)blockIdx.x * rows_per_block;
    for (int r = 0; r < rows_per_block; ++r) {
        long s = row0 + r;
        if (s >= S) break;
        float eff = a_s * (0.5f + 0.5f * ((float)s * invS));
        float dn = fabsf(eff) * mnorm;
        float coef = (dn > 0.5f) ? (eff * (0.5f / dn)) : eff;
        for (int j = 0; j < jn; ++j) {
            long idx = s * (long)D4 + (j << 8) + tid;
            float4 m;
            if (cached) {
                m = mv[j];
            } else {
                int d4 = (j << 8) + tid;
                float4 c = c4p[d4], iv = i4p[d4];
                m.x = (c.x - iv.x) * inv_nd; m.y = (c.y - iv.y) * inv_nd;
                m.z = (c.z - iv.z) * inv_nd; m.w = (c.w - iv.w) * inv_nd;
            }
            float4 h = h4[idx];
            nfloat4 rr;
            rr.x = h.x + coef * m.x;
            rr.y = h.y + coef * m.y;
            rr.z = h.z + coef * m.z;
            rr.w = h.w + coef * m.w;
            __builtin_nontemporal_store(rr, &o4[idx]);
        }
    }
}

extern "C" void kernel_launch(void* const* d_in, const int* in_sizes, int n_in,
                              void* d_out, int out_size, void* d_ws, size_t ws_size,
                              hipStream_t stream) {
    const float* hid    = (const float*)d_in[0];
    const float* cdir   = (const float*)d_in[1];
    const float* idir   = (const float*)d_in[2];
    const float* sscale = (const float*)d_in[3];
    float* out = (float*)d_out;

    int D = in_sizes[1];                 // 4096
    long total = (long)in_sizes[0];      // B*S*D, B=1
    int S = (int)(total / D);            // 8192
    int D4 = D / 4;

    const int C = 256;                   // chunks along S
    int rows_per_chunk = (S + C - 1) / C;

    float* partial = (float*)d_ws;                       // C*D floats
    float* ws6 = partial + (size_t)C * D;                // NB*6 floats

    dim3 g1((D4 + 255) / 256, C);
    ara_colsum<<<g1, 256, 0, stream>>>(hid, partial, D4, S, rows_per_chunk);

    int NB = (D4 + 63) / 64;             // 16 for D=4096
    ara_reduce<<<NB, 256, 0, stream>>>(partial, cdir, idir, ws6, D4, C);

    int rows_per_block = 4;
    int g3 = (S + rows_per_block - 1) / rows_per_block;  // 2048
    ara_apply<<<g3, 256, 0, stream>>>(hid, cdir, idir, sscale, ws6, out,
                                      D4, S, NB, rows_per_block);
}

// Round 5
// 98.162 us; speedup vs baseline: 2.6378x; 1.0460x over previous
//
#include <hip/hip_runtime.h>
#include <math.h>

#define EPSV 1e-12f

// ---------- Kernel 1: partial column sums (deterministic, no atomics) ----------
// grid = (D4/256, C). partial[c][D] as float4.
__global__ __launch_bounds__(256)
void ara_colsum(const float* __restrict__ hid, float* __restrict__ partial,
                int D4, int S, int rows_per_chunk) {
    int d4 = blockIdx.x * 256 + threadIdx.x;
    if (d4 >= D4) return;
    int c = blockIdx.y;
    const float4* h4 = reinterpret_cast<const float4*>(hid);
    float4* p4 = reinterpret_cast<float4*>(partial);
    long row0 = (long)c * rows_per_chunk;
    float4 acc = make_float4(0.f, 0.f, 0.f, 0.f);
#pragma unroll 8
    for (int r = 0; r < rows_per_chunk; ++r) {
        long row = row0 + r;
        if (row < S) {
            float4 v = h4[row * (long)D4 + d4];
            acc.x += v.x; acc.y += v.y; acc.z += v.z; acc.w += v.w;
        }
    }
    p4[(long)c * D4 + d4] = acc;
}

// ---------- Kernel 2: reduce partials + 6 dot products ----------
// grid = NB = ceil(D4/64) blocks x 256 threads. Block b owns float4 cols
// [b*64, b*64+64). 4 thread-groups of 64 lanes each sum C/4 chunks.
// Writes ws6[b][6] = {||c||^2, ||i||^2, sums.c, sums.i, ||sums||^2, ||c-i||^2}.
__global__ __launch_bounds__(256)
void ara_reduce(const float* __restrict__ partial, const float* __restrict__ cdir,
                const float* __restrict__ idir, float* __restrict__ ws6,
                int D4, int C) {
    const float4* p4 = reinterpret_cast<const float4*>(partial);
    const float4* c4p = reinterpret_cast<const float4*>(cdir);
    const float4* i4p = reinterpret_cast<const float4*>(idir);
    int lane = threadIdx.x & 63;
    int g = threadIdx.x >> 6;                 // 0..3
    int col = blockIdx.x * 64 + lane;
    bool valid = col < D4;
    int per = (C + 3) / 4;
    float4 acc = make_float4(0.f, 0.f, 0.f, 0.f);
    if (valid) {
        for (int j = 0; j < per; ++j) {
            int c = g * per + j;
            if (c < C) {
                float4 v = p4[(long)c * D4 + col];
                acc.x += v.x; acc.y += v.y; acc.z += v.z; acc.w += v.w;
            }
        }
    }
    __shared__ float4 lds[4][64];
    lds[g][lane] = acc;
    __syncthreads();
    if (threadIdx.x < 64) {
        float vals[6] = {0.f, 0.f, 0.f, 0.f, 0.f, 0.f};
        if (valid) {
            float4 s;
            s.x = lds[0][lane].x + lds[1][lane].x + lds[2][lane].x + lds[3][lane].x;
            s.y = lds[0][lane].y + lds[1][lane].y + lds[2][lane].y + lds[3][lane].y;
            s.z = lds[0][lane].z + lds[1][lane].z + lds[2][lane].z + lds[3][lane].z;
            s.w = lds[0][lane].w + lds[1][lane].w + lds[2][lane].w + lds[3][lane].w;
            float4 c = c4p[col], iv = i4p[col];
            vals[0] = c.x*c.x + c.y*c.y + c.z*c.z + c.w*c.w;
            vals[1] = iv.x*iv.x + iv.y*iv.y + iv.z*iv.z + iv.w*iv.w;
            vals[2] = s.x*c.x + s.y*c.y + s.z*c.z + s.w*c.w;
            vals[3] = s.x*iv.x + s.y*iv.y + s.z*iv.z + s.w*iv.w;
            vals[4] = s.x*s.x + s.y*s.y + s.z*s.z + s.w*s.w;
            float dx = c.x-iv.x, dy = c.y-iv.y, dz = c.z-iv.z, dw = c.w-iv.w;
            vals[5] = dx*dx + dy*dy + dz*dz + dw*dw;
        }
#pragma unroll
        for (int k = 0; k < 6; ++k) {
            float v = vals[k];
#pragma unroll
            for (int o = 32; o > 0; o >>= 1) v += __shfl_down(v, o, 64);
            if (lane == 0) ws6[blockIdx.x * 6 + k] = v;
        }
    }
}

// ---------- Kernel 3: apply ----------
// grid = ceil(S/rows_per_block) x 256. Per-block preamble sums ws6 (deterministic)
// and computes alpha; main loop streams rows with regular float4 stores.
__global__ __launch_bounds__(256)
void ara_apply(const float* __restrict__ hid, const float* __restrict__ cdir,
               const float* __restrict__ idir, const float* __restrict__ sscale,
               const float* __restrict__ ws6, float* __restrict__ out,
               int D4, int S, int NB, int rows_per_block) {
    __shared__ float lds[256];
    __shared__ float bc[3];
    int tid = threadIdx.x;
    int n6 = NB * 6;
    if (tid < n6 && tid < 256) lds[tid] = ws6[tid];
    __syncthreads();
    if (tid == 0) {
        float t[6] = {0.f, 0.f, 0.f, 0.f, 0.f, 0.f};
        for (int b = 0; b < NB; ++b)
#pragma unroll
            for (int k = 0; k < 6; ++k) t[k] += lds[b * 6 + k];
        float invS = 1.0f / (float)S;
        float cn = sqrtf(t[4]) * invS;                  // ||mean||
        float inv_cn = 1.0f / fmaxf(cn, EPSV);
        float csim = (sqrtf(t[0]) > 0.f) ? (t[2] * invS * inv_cn) : 0.f;
        float isim = (sqrtf(t[1]) > 0.f) ? (t[3] * invS * inv_cn) : 0.f;
        float quality = csim - isim;
        float amp = 0.5f * (0.1f - quality) / (0.1f + 0.3f);
        float alpha = (quality < -0.3f) ? 0.5f : ((quality < 0.1f) ? amp : 0.05f);
        float ndiff = sqrtf(t[5]);
        float inv_nd = 1.0f / fmaxf(ndiff, EPSV);
        bc[0] = alpha * sscale[0];
        bc[1] = inv_nd;
        bc[2] = ndiff * inv_nd;                         // ||momentum||
    }
    __syncthreads();
    const float a_s = bc[0], inv_nd = bc[1], mnorm = bc[2];
    const float invS = 1.0f / (float)S;

    const float4* h4 = reinterpret_cast<const float4*>(hid);
    const float4* c4p = reinterpret_cast<const float4*>(cdir);
    const float4* i4p = reinterpret_cast<const float4*>(idir);
    float4* o4 = reinterpret_cast<float4*>(out);

    int jn = D4 >> 8;                                   // strips of 256 float4
    float4 mv[4];
    bool cached = (jn <= 4);
    for (int j = 0; j < jn && j < 4; ++j) {
        int d4 = (j << 8) + tid;
        float4 c = c4p[d4], iv = i4p[d4];
        mv[j].x = (c.x - iv.x) * inv_nd;
        mv[j].y = (c.y - iv.y) * inv_nd;
        mv[j].z = (c.z - iv.z) * inv_nd;
        mv[j].w = (c.w - iv.w) * inv_nd;
    }
    long row0 = (long)blockIdx.x * rows_per_block;
    for (int r = 0; r < rows_per_block; ++r) {
        long s = row0 + r;
        if (s >= S) break;
        float eff = a_s * (0.5f + 0.5f * ((float)s * invS));
        float dn = fabsf(eff) * mnorm;
        float coef = (dn > 0.5f) ? (eff * (0.5f / dn)) : eff;
        for (int j = 0; j < jn; ++j) {
            long idx = s * (long)D4 + (j << 8) + tid;
            float4 m;
            if (cached) {
                m = mv[j];
            } else {
                int d4 = (j << 8) + tid;
                float4 c = c4p[d4], iv = i4p[d4];
                m.x = (c.x - iv.x) * inv_nd; m.y = (c.y - iv.y) * inv_nd;
                m.z = (c.z - iv.z) * inv_nd; m.w = (c.w - iv.w) * inv_nd;
            }
            float4 h = h4[idx];
            float4 rr;
            rr.x = h.x + coef * m.x;
            rr.y = h.y + coef * m.y;
            rr.z = h.z + coef * m.z;
            rr.w = h.w + coef * m.w;
            o4[idx] = rr;
        }
    }
}

extern "C" void kernel_launch(void* const* d_in, const int* in_sizes, int n_in,
                              void* d_out, int out_size, void* d_ws, size_t ws_size,
                              hipStream_t stream) {
    const float* hid    = (const float*)d_in[0];
    const float* cdir   = (const float*)d_in[1];
    const float* idir   = (const float*)d_in[2];
    const float* sscale = (const float*)d_in[3];
    float* out = (float*)d_out;

    int D = in_sizes[1];                 // 4096
    long total = (long)in_sizes[0];      // B*S*D, B=1
    int S = (int)(total / D);            // 8192
    int D4 = D / 4;

    const int C = 128;                   // chunks along S
    int rows_per_chunk = (S + C - 1) / C;

    float* partial = (float*)d_ws;                       // C*D floats
    float* ws6 = partial + (size_t)C * D;                // NB*6 floats

    dim3 g1((D4 + 255) / 256, C);
    ara_colsum<<<g1, 256, 0, stream>>>(hid, partial, D4, S, rows_per_chunk);

    int NB = (D4 + 63) / 64;             // 16 for D=4096
    ara_reduce<<<NB, 256, 0, stream>>>(partial, cdir, idir, ws6, D4, C);

    int rows_per_block = 4;
    int g3 = (S + rows_per_block - 1) / rows_per_block;  // 2048
    ara_apply<<<g3, 256, 0, stream>>>(hid, cdir, idir, sscale, ws6, out,
                                      D4, S, NB, rows_per_block);
}